// Round 11
// baseline (83.391 us; speedup 1.0000x reference)
//
#include <hip/hip_runtime.h>

typedef __attribute__((ext_vector_type(8))) short bf16x8;
typedef __attribute__((ext_vector_type(4))) float f32x4;
typedef __attribute__((ext_vector_type(16))) float f32x16;
typedef __attribute__((ext_vector_type(8))) unsigned short us8;
typedef unsigned short u16;
typedef unsigned int u32;

__device__ inline u16 f2bf(float f) {
  union { float f; unsigned u; } v; v.f = f;
  unsigned r = v.u + 0x7FFFu + ((v.u >> 16) & 1u);  // RNE
  return (u16)(r >> 16);
}

__device__ inline u32 cvtpk_bf16(float lo, float hi) {
  u32 r;
  asm volatile("v_cvt_pk_bf16_f32 %0, %1, %2" : "=v"(r) : "v"(lo), "v"(hi));
  return r;
}

__device__ inline void gload_lds16(const void* g, void* l) {
  __builtin_amdgcn_global_load_lds(
      (const __attribute__((address_space(1))) void*)g,
      (__attribute__((address_space(3))) void*)l, 16, 0, 0);
}

// ---------------- fused convert f32 -> bf16 (x, Wq, Wk, Wv in one launch) ----------------
__global__ void cvt_all(const float* __restrict__ x, const float* __restrict__ wq,
                        const float* __restrict__ wk, const float* __restrict__ wv,
                        u16* __restrict__ out) {
  int i = (blockIdx.x * blockDim.x + threadIdx.x) * 4;
  const float* src; int off;
  if (i < 4194304)      { src = x;  off = 0; }
  else if (i < 5242880) { src = wq; off = 4194304; }
  else if (i < 6291456) { src = wk; off = 5242880; }
  else                  { src = wv; off = 6291456; }
  float4 v = *reinterpret_cast<const float4*>(src + (i - off));
  ushort4 o;
  o.x = f2bf(v.x); o.y = f2bf(v.y); o.z = f2bf(v.z); o.w = f2bf(v.w);
  *reinterpret_cast<ushort4*>(out + i) = o;
}

// ---------------- QKV projection GEMM: out = x @ W.T + b ----------------
// z==0: Q (scaled, [bh][n][64]); z==1: K ([bh][n][64]); z==2: V TRANSPOSED ([bh][d][2048]).
__global__ __launch_bounds__(256, 3) void gemm_qkv(
    const u16* __restrict__ X,
    const u16* __restrict__ Wq, const u16* __restrict__ Wk, const u16* __restrict__ Wv,
    const float* __restrict__ bq, const float* __restrict__ bk, const float* __restrict__ bv,
    u16* __restrict__ Oq, u16* __restrict__ Ok, u16* __restrict__ Ovt)
{
  constexpr int GK = 1024;
  __shared__ __align__(16) u16 As[128 * 64];
  __shared__ __align__(16) u16 Bs[128 * 64];

  const int z = blockIdx.z;
  const u16* W = (z == 0) ? Wq : (z == 1) ? Wk : Wv;
  const float* bias = (z == 0) ? bq : (z == 1) ? bk : bv;
  const float scale = (z == 0) ? (1.4426950408889634f / 32.0f) : 1.0f;

  const int tid = threadIdx.x;
  const int lane = tid & 63, w = tid >> 6;
  const int wm = w >> 1, wn = w & 1;
  const int q = lane & 15, g = lane >> 4;
  const int bm0 = blockIdx.x * 128, bn0 = blockIdx.y * 128;

  int srow[4], sgc[4];
  #pragma unroll
  for (int i = 0; i < 4; ++i) {
    int c = i * 256 + tid;
    srow[i] = c >> 3;
    sgc[i] = (((c & 7) ^ ((c >> 3) & 7)) * 8);
  }

  f32x4 acc[4][4];
  #pragma unroll
  for (int i = 0; i < 4; ++i)
    #pragma unroll
    for (int j = 0; j < 4; ++j) acc[i][j] = (f32x4){0.f, 0.f, 0.f, 0.f};

  for (int k0 = 0; k0 < GK; k0 += 64) {
    #pragma unroll
    for (int i = 0; i < 4; ++i) {
      int c8 = (i * 256 + tid) * 8;
      gload_lds16(&X[(bm0 + srow[i]) * GK + k0 + sgc[i]], &As[c8]);
      gload_lds16(&W[(bn0 + srow[i]) * GK + k0 + sgc[i]], &Bs[c8]);
    }
    __syncthreads();

    #pragma unroll
    for (int kk = 0; kk < 2; ++kk) {
      bf16x8 af[4], bfr[4];
      #pragma unroll
      for (int mi = 0; mi < 4; ++mi) {
        int row = wm * 64 + mi * 16 + q;
        af[mi] = *reinterpret_cast<const bf16x8*>(
            &As[row * 64 + (((kk * 4 + g) ^ (row & 7)) * 8)]);
      }
      #pragma unroll
      for (int ni = 0; ni < 4; ++ni) {
        int row = wn * 64 + ni * 16 + q;
        bfr[ni] = *reinterpret_cast<const bf16x8*>(
            &Bs[row * 64 + (((kk * 4 + g) ^ (row & 7)) * 8)]);
      }
      #pragma unroll
      for (int mi = 0; mi < 4; ++mi)
        #pragma unroll
        for (int ni = 0; ni < 4; ++ni)
          acc[mi][ni] = __builtin_amdgcn_mfma_f32_16x16x32_bf16(af[mi], bfr[ni], acc[mi][ni], 0, 0, 0);
    }
    __syncthreads();
  }

  if (z == 2) {
    // V epilogue: write transposed Vt[((b*16+h)*64 + d)*2048 + n], 4 consecutive n
    #pragma unroll
    for (int mi = 0; mi < 4; ++mi) {
      #pragma unroll
      for (int ni = 0; ni < 4; ++ni) {
        int col = bn0 + wn * 64 + ni * 16 + q;
        float bb = bias[col];
        int h = col >> 6, d = col & 63;
        int row0 = bm0 + wm * 64 + mi * 16 + 4 * g;
        int b = row0 >> 11, n0 = row0 & 2047;
        ushort4 o4;
        o4.x = f2bf(acc[mi][ni][0] + bb);
        o4.y = f2bf(acc[mi][ni][1] + bb);
        o4.z = f2bf(acc[mi][ni][2] + bb);
        o4.w = f2bf(acc[mi][ni][3] + bb);
        *reinterpret_cast<ushort4*>(&Ovt[(((b << 4) + h) * 64 + d) * 2048 + n0]) = o4;
      }
    }
  } else {
    u16* O = (z == 0) ? Oq : Ok;
    #pragma unroll
    for (int mi = 0; mi < 4; ++mi) {
      #pragma unroll
      for (int ni = 0; ni < 4; ++ni) {
        int col = bn0 + wn * 64 + ni * 16 + q;
        float bb = bias[col];
        int h = col >> 6, d = col & 63;
        #pragma unroll
        for (int r = 0; r < 4; ++r) {
          int row = bm0 + wm * 64 + mi * 16 + 4 * g + r;
          int b = row >> 11, n = row & 2047;
          float v = (acc[mi][ni][r] + bb) * scale;
          O[(((b << 4) + h) * 2048 + n) * 64 + d] = f2bf(v);
        }
      }
    }
  }
}

// ---------------- flash attention: 8 waves, KV split in halves ----------------
// Waves 0-3: keys [0,1024); waves 4-7: keys [1024,2048), same 128 q-rows.
// Static-max softmax => linear split-K combine. Swapped QK^T; O^T = V^T @ P^T.
// K/V^T staged via global_load_lds (pre-inverse-swizzled source), 2-deep.
// T3/T4: raw s_barrier per tile + COUNTED vmcnt waits (6 before QK, 4 before V
// reads) -- next-tile DMAs are never drained inside the tile that issued them.
__global__ __launch_bounds__(512, 4) void attn_kernel(
    const u16* __restrict__ Q, const u16* __restrict__ K, const u16* __restrict__ Vt,
    float* __restrict__ out)
{
  __shared__ __align__(16) u16 smem[32768];   // 64KB: K[half][buf][4096] | V[half][buf][4096]
  u16* Kbase = smem;
  u16* Vbase = smem + 16384;

  const int tid = threadIdx.x;
  const int lane = tid & 63, w = tid >> 6;          // 8 waves
  const int half = w >> 2, w4 = w & 3;
  const int tid256 = w4 * 64 + lane;
  const int ql = lane & 31, h = lane >> 5, l7 = lane & 7;

  // XCD swizzle: xcd = lin&7 owns bh in [xcd*4, xcd*4+4)
  const int lin = blockIdx.x;
  const int xcd = lin & 7, li = lin >> 3;
  const int bh = xcd * 4 + (li >> 4);
  const int b = bh >> 4, hd = bh & 15;
  const int qrow0 = (li & 15) * 128 + w4 * 32;

  const u16* Qp = Q + (bh * 2048 + qrow0 + ql) * 64;
  const u16* Kp = K + (bh * 2048 + half * 1024) * 64;
  const u16* Vp = Vt + bh * 64 * 2048 + half * 1024;  // [64 d][2048 n], n-range offset

  // Q fragments (B-operand): lane holds Q[qrow0+ql][16*ks + 8*h + j]
  bf16x8 qf[4];
  #pragma unroll
  for (int ks = 0; ks < 4; ++ks)
    qf[ks] = *reinterpret_cast<const bf16x8*>(Qp + 16 * ks + 8 * h);

  // staging geometry (per half): chunk c = i*256 + tid256 of 512 16B-chunks.
  int krow_i[2], kcolb_i[2];
  #pragma unroll
  for (int i = 0; i < 2; ++i) {
    int c = i * 256 + tid256;
    krow_i[i] = c >> 3;
    kcolb_i[i] = 16 * ((c & 7) ^ ((c >> 3) & 7));
  }

  f32x16 o0, o1;
  #pragma unroll
  for (int i = 0; i < 16; ++i) { o0[i] = 0.0f; o1[i] = 0.0f; }
  float lsum = 0.0f;

  u16* Kh = Kbase + half * 8192;
  u16* Vh = Vbase + half * 8192;

  // prologue: stage tile 0 (full drain once; also drains Q loads)
  {
    #pragma unroll
    for (int i = 0; i < 2; ++i)
      gload_lds16((const char*)(Kp + krow_i[i] * 64) + kcolb_i[i],
                  &Kh[i * 2048 + w4 * 512]);
    #pragma unroll
    for (int i = 0; i < 2; ++i)
      gload_lds16((const char*)(Vp + krow_i[i] * 2048) + kcolb_i[i],
                  &Vh[i * 2048 + w4 * 512]);
    __syncthreads();
  }

  for (int t = 0; t < 16; ++t) {
    const int cur = t & 1, nxt = cur ^ 1;
    const int kb = t * 64;
    // issue next-tile DMA; t==15 issues a clamped dummy refetch (uniform counts)
    const int kbn = (t < 15) ? (kb + 64) : kb;
    #pragma unroll
    for (int i = 0; i < 2; ++i)
      gload_lds16((const char*)(Kp + (kbn + krow_i[i]) * 64) + kcolb_i[i],
                  &Kh[nxt * 4096 + i * 2048 + w4 * 512]);
    #pragma unroll
    for (int i = 0; i < 2; ++i)
      gload_lds16((const char*)(Vp + krow_i[i] * 2048 + kbn) + kcolb_i[i],
                  &Vh[nxt * 4096 + i * 2048 + w4 * 512]);

    // K(t) ready: the 6 newer ops (V(t) x2 + next-tile x4) may stay in flight
    asm volatile("s_waitcnt vmcnt(6)" ::: "memory");
    __builtin_amdgcn_sched_barrier(0);

    // ---- QK^T: p[s] = K[32s..32s+31] @ Q^T (accumulate over 4 k-slices) ----
    f32x16 p0, p1;
    #pragma unroll
    for (int i = 0; i < 16; ++i) { p0[i] = 0.0f; p1[i] = 0.0f; }
    const u16* kl = Kh + cur * 4096;
    __builtin_amdgcn_s_setprio(1);
    #pragma unroll
    for (int ks = 0; ks < 4; ++ks) {
      int cb = (16 * ks + 8 * h) ^ (l7 << 3);
      bf16x8 kf0 = *reinterpret_cast<const bf16x8*>(kl + ql * 64 + cb);
      p0 = __builtin_amdgcn_mfma_f32_32x32x16_bf16(kf0, qf[ks], p0, 0, 0, 0);
      bf16x8 kf1 = *reinterpret_cast<const bf16x8*>(kl + (32 + ql) * 64 + cb);
      p1 = __builtin_amdgcn_mfma_f32_32x32x16_bf16(kf1, qf[ks], p1, 0, 0, 0);
    }
    __builtin_amdgcn_s_setprio(0);

    // V(t) ready: only next-tile's 4 ops remain in flight
    asm volatile("s_waitcnt vmcnt(4)" ::: "memory");
    __builtin_amdgcn_sched_barrier(0);

    // ---- hoisted V-fragment reads (latency hides under softmax VALU) ----
    const u16* vl = Vh + cur * 4096;
    bf16x8 vf0a[4];
    #pragma unroll
    for (int f = 0; f < 4; ++f) {
      int cb = (16 * f + 8 * h) ^ (l7 << 3);
      vf0a[f] = *reinterpret_cast<const bf16x8*>(vl + ql * 64 + cb);
    }

    // ---- static-max softmax (log2 domain; Q pre-scaled by log2e/32) ----
    #pragma unroll
    for (int i = 0; i < 16; ++i) {
      p0[i] = __builtin_amdgcn_exp2f(p0[i]);
      p1[i] = __builtin_amdgcn_exp2f(p1[i]);
    }
    float sa[8];
    #pragma unroll
    for (int i = 0; i < 8; ++i)
      sa[i] = (p0[i] + p0[i + 8]) + (p1[i] + p1[i + 8]);
    float rs = ((sa[0] + sa[1]) + (sa[2] + sa[3])) + ((sa[4] + sa[5]) + (sa[6] + sa[7]));
    rs += __shfl_xor(rs, 32);
    lsum += rs;

    // ---- P^T -> bf16 B-fragments via cvt_pk + permlane32_swap (T12) ----
    bf16x8 pf[4];
    {
      union { u32 u[4]; bf16x8 v; } fr;
      u32 a0 = cvtpk_bf16(p0[0], p0[1]),   c0 = cvtpk_bf16(p0[2], p0[3]);
      u32 b0 = cvtpk_bf16(p0[4], p0[5]),   d0 = cvtpk_bf16(p0[6], p0[7]);
      asm volatile("v_permlane32_swap_b32 %0, %1" : "+v"(a0), "+v"(b0));
      asm volatile("v_permlane32_swap_b32 %0, %1" : "+v"(c0), "+v"(d0));
      fr.u[0] = a0; fr.u[1] = c0; fr.u[2] = b0; fr.u[3] = d0;  pf[0] = fr.v;
      u32 a1 = cvtpk_bf16(p0[8], p0[9]),   c1 = cvtpk_bf16(p0[10], p0[11]);
      u32 b1 = cvtpk_bf16(p0[12], p0[13]), d1 = cvtpk_bf16(p0[14], p0[15]);
      asm volatile("v_permlane32_swap_b32 %0, %1" : "+v"(a1), "+v"(b1));
      asm volatile("v_permlane32_swap_b32 %0, %1" : "+v"(c1), "+v"(d1));
      fr.u[0] = a1; fr.u[1] = c1; fr.u[2] = b1; fr.u[3] = d1;  pf[1] = fr.v;
      u32 a2 = cvtpk_bf16(p1[0], p1[1]),   c2 = cvtpk_bf16(p1[2], p1[3]);
      u32 b2 = cvtpk_bf16(p1[4], p1[5]),   d2 = cvtpk_bf16(p1[6], p1[7]);
      asm volatile("v_permlane32_swap_b32 %0, %1" : "+v"(a2), "+v"(b2));
      asm volatile("v_permlane32_swap_b32 %0, %1" : "+v"(c2), "+v"(d2));
      fr.u[0] = a2; fr.u[1] = c2; fr.u[2] = b2; fr.u[3] = d2;  pf[2] = fr.v;
      u32 a3 = cvtpk_bf16(p1[8], p1[9]),   c3 = cvtpk_bf16(p1[10], p1[11]);
      u32 b3 = cvtpk_bf16(p1[12], p1[13]), d3 = cvtpk_bf16(p1[14], p1[15]);
      asm volatile("v_permlane32_swap_b32 %0, %1" : "+v"(a3), "+v"(b3));
      asm volatile("v_permlane32_swap_b32 %0, %1" : "+v"(c3), "+v"(d3));
      fr.u[0] = a3; fr.u[1] = c3; fr.u[2] = b3; fr.u[3] = d3;  pf[3] = fr.v;
    }

    // ---- PV: O^T[dt] += V^T-slice @ P^T-slice ----
    __builtin_amdgcn_s_setprio(1);
    #pragma unroll
    for (int f = 0; f < 4; ++f) {
      int cb = (16 * f + 8 * h) ^ (l7 << 3);
      o0 = __builtin_amdgcn_mfma_f32_32x32x16_bf16(vf0a[f], pf[f], o0, 0, 0, 0);
      bf16x8 vf1 = *reinterpret_cast<const bf16x8*>(vl + (32 + ql) * 64 + cb);
      o1 = __builtin_amdgcn_mfma_f32_32x32x16_bf16(vf1, pf[f], o1, 0, 0, 0);
    }
    __builtin_amdgcn_s_setprio(0);

    // raw barrier: orders next iteration's DMA overwrite after all reads of
    // buf[cur]; deliberately NO vmcnt drain (that was the per-tile stall).
    __builtin_amdgcn_s_barrier();
  }

  // ---- combine halves in LDS ----
  float* Of = reinterpret_cast<float*>(smem);
  float* Lf = Of + 4 * 64 * 33;
  const int obase = (w4 * 64 + lane) * 33;
  if (half == 1) {
    #pragma unroll
    for (int i = 0; i < 16; ++i) { Of[obase + i] = o0[i]; Of[obase + 16 + i] = o1[i]; }
    Lf[w4 * 64 + lane] = lsum;
  }
  __syncthreads();
  if (half == 0) {
    #pragma unroll
    for (int i = 0; i < 16; ++i) { o0[i] += Of[obase + i]; o1[i] += Of[obase + 16 + i]; }
    lsum += Lf[w4 * 64 + lane];

    float r = 1.0f / lsum;
    float* op = out + ((size_t)(b * 2048 + qrow0 + ql) * 1024 + hd * 64);
    #pragma unroll
    for (int g2 = 0; g2 < 4; ++g2) {
      float4 v0, v1;
      v0.x = o0[4 * g2 + 0] * r; v0.y = o0[4 * g2 + 1] * r;
      v0.z = o0[4 * g2 + 2] * r; v0.w = o0[4 * g2 + 3] * r;
      v1.x = o1[4 * g2 + 0] * r; v1.y = o1[4 * g2 + 1] * r;
      v1.z = o1[4 * g2 + 2] * r; v1.w = o1[4 * g2 + 3] * r;
      *reinterpret_cast<float4*>(op + 8 * g2 + 4 * h)      = v0;
      *reinterpret_cast<float4*>(op + 32 + 8 * g2 + 4 * h) = v1;
    }
  }
}

extern "C" void kernel_launch(void* const* d_in, const int* in_sizes, int n_in,
                              void* d_out, int out_size, void* d_ws, size_t ws_size,
                              hipStream_t stream) {
  const float* x  = (const float*)d_in[0];
  const float* Wq = (const float*)d_in[1];
  const float* bq = (const float*)d_in[2];
  const float* Wk = (const float*)d_in[3];
  const float* bk = (const float*)d_in[4];
  const float* Wv = (const float*)d_in[5];
  const float* bv = (const float*)d_in[6];
  float* out = (float*)d_out;

  u16* ws  = (u16*)d_ws;
  u16* xb  = ws;                  // 4096*1024
  u16* wqb = xb  + 4194304;       // 1024*1024
  u16* wkb = wqb + 1048576;
  u16* wvb = wkb + 1048576;
  u16* qb  = wvb + 1048576;       // [32][2048][64]
  u16* kb  = qb  + 4194304;
  u16* vt  = kb  + 4194304;       // [32][64][2048] (written transposed by gemm z==2)

  cvt_all<<<7168, 256, 0, stream>>>(x, Wq, Wk, Wv, ws);

  gemm_qkv<<<dim3(32, 8, 3), 256, 0, stream>>>(xb, wqb, wkb, wvb, bq, bk, bv, qb, kb, vt);

  attn_kernel<<<512, 512, 0, stream>>>(qb, kb, vt, out);
}

// Round 12
// 81.676 us; speedup vs baseline: 1.0210x; 1.0210x over previous
//
#include <hip/hip_runtime.h>

typedef __attribute__((ext_vector_type(8))) short bf16x8;
typedef __attribute__((ext_vector_type(4))) float f32x4;
typedef __attribute__((ext_vector_type(16))) float f32x16;
typedef __attribute__((ext_vector_type(8))) unsigned short us8;
typedef unsigned short u16;
typedef unsigned int u32;

__device__ inline u16 f2bf(float f) {
  union { float f; unsigned u; } v; v.f = f;
  unsigned r = v.u + 0x7FFFu + ((v.u >> 16) & 1u);  // RNE
  return (u16)(r >> 16);
}

__device__ inline u32 cvtpk_bf16(float lo, float hi) {
  u32 r;
  asm volatile("v_cvt_pk_bf16_f32 %0, %1, %2" : "=v"(r) : "v"(lo), "v"(hi));
  return r;
}

__device__ inline void gload_lds16(const void* g, void* l) {
  __builtin_amdgcn_global_load_lds(
      (const __attribute__((address_space(1))) void*)g,
      (__attribute__((address_space(3))) void*)l, 16, 0, 0);
}

// T12: one 32-krow P^T subtile (16 f32) -> two bf16x8 B-fragments (verified R3+)
__device__ inline void p_to_pf(const f32x16& p, bf16x8& f0, bf16x8& f1) {
  union { u32 u[4]; bf16x8 v; } fr;
  u32 a = cvtpk_bf16(p[0], p[1]),   c = cvtpk_bf16(p[2], p[3]);
  u32 b = cvtpk_bf16(p[4], p[5]),   d = cvtpk_bf16(p[6], p[7]);
  asm volatile("v_permlane32_swap_b32 %0, %1" : "+v"(a), "+v"(b));
  asm volatile("v_permlane32_swap_b32 %0, %1" : "+v"(c), "+v"(d));
  fr.u[0] = a; fr.u[1] = c; fr.u[2] = b; fr.u[3] = d;  f0 = fr.v;
  u32 a2 = cvtpk_bf16(p[8], p[9]),   c2 = cvtpk_bf16(p[10], p[11]);
  u32 b2 = cvtpk_bf16(p[12], p[13]), d2 = cvtpk_bf16(p[14], p[15]);
  asm volatile("v_permlane32_swap_b32 %0, %1" : "+v"(a2), "+v"(b2));
  asm volatile("v_permlane32_swap_b32 %0, %1" : "+v"(c2), "+v"(d2));
  fr.u[0] = a2; fr.u[1] = c2; fr.u[2] = b2; fr.u[3] = d2;  f1 = fr.v;
}

// ---------------- fused convert f32 -> bf16 (x, Wq, Wk, Wv in one launch) ----------------
__global__ void cvt_all(const float* __restrict__ x, const float* __restrict__ wq,
                        const float* __restrict__ wk, const float* __restrict__ wv,
                        u16* __restrict__ out) {
  int i = (blockIdx.x * blockDim.x + threadIdx.x) * 4;
  const float* src; int off;
  if (i < 4194304)      { src = x;  off = 0; }
  else if (i < 5242880) { src = wq; off = 4194304; }
  else if (i < 6291456) { src = wk; off = 5242880; }
  else                  { src = wv; off = 6291456; }
  float4 v = *reinterpret_cast<const float4*>(src + (i - off));
  ushort4 o;
  o.x = f2bf(v.x); o.y = f2bf(v.y); o.z = f2bf(v.z); o.w = f2bf(v.w);
  *reinterpret_cast<ushort4*>(out + i) = o;
}

// ---------------- QKV projection GEMM: out = x @ W.T + b ----------------
// z==0: Q (scaled, [bh][n][64]); z==1: K ([bh][n][64]); z==2: V TRANSPOSED ([bh][d][2048]).
__global__ __launch_bounds__(256, 3) void gemm_qkv(
    const u16* __restrict__ X,
    const u16* __restrict__ Wq, const u16* __restrict__ Wk, const u16* __restrict__ Wv,
    const float* __restrict__ bq, const float* __restrict__ bk, const float* __restrict__ bv,
    u16* __restrict__ Oq, u16* __restrict__ Ok, u16* __restrict__ Ovt)
{
  constexpr int GK = 1024;
  __shared__ __align__(16) u16 As[128 * 64];
  __shared__ __align__(16) u16 Bs[128 * 64];

  const int z = blockIdx.z;
  const u16* W = (z == 0) ? Wq : (z == 1) ? Wk : Wv;
  const float* bias = (z == 0) ? bq : (z == 1) ? bk : bv;
  const float scale = (z == 0) ? (1.4426950408889634f / 32.0f) : 1.0f;

  const int tid = threadIdx.x;
  const int lane = tid & 63, w = tid >> 6;
  const int wm = w >> 1, wn = w & 1;
  const int q = lane & 15, g = lane >> 4;
  const int bm0 = blockIdx.x * 128, bn0 = blockIdx.y * 128;

  int srow[4], sgc[4];
  #pragma unroll
  for (int i = 0; i < 4; ++i) {
    int c = i * 256 + tid;
    srow[i] = c >> 3;
    sgc[i] = (((c & 7) ^ ((c >> 3) & 7)) * 8);
  }

  f32x4 acc[4][4];
  #pragma unroll
  for (int i = 0; i < 4; ++i)
    #pragma unroll
    for (int j = 0; j < 4; ++j) acc[i][j] = (f32x4){0.f, 0.f, 0.f, 0.f};

  for (int k0 = 0; k0 < GK; k0 += 64) {
    #pragma unroll
    for (int i = 0; i < 4; ++i) {
      int c8 = (i * 256 + tid) * 8;
      gload_lds16(&X[(bm0 + srow[i]) * GK + k0 + sgc[i]], &As[c8]);
      gload_lds16(&W[(bn0 + srow[i]) * GK + k0 + sgc[i]], &Bs[c8]);
    }
    __syncthreads();

    #pragma unroll
    for (int kk = 0; kk < 2; ++kk) {
      bf16x8 af[4], bfr[4];
      #pragma unroll
      for (int mi = 0; mi < 4; ++mi) {
        int row = wm * 64 + mi * 16 + q;
        af[mi] = *reinterpret_cast<const bf16x8*>(
            &As[row * 64 + (((kk * 4 + g) ^ (row & 7)) * 8)]);
      }
      #pragma unroll
      for (int ni = 0; ni < 4; ++ni) {
        int row = wn * 64 + ni * 16 + q;
        bfr[ni] = *reinterpret_cast<const bf16x8*>(
            &Bs[row * 64 + (((kk * 4 + g) ^ (row & 7)) * 8)]);
      }
      #pragma unroll
      for (int mi = 0; mi < 4; ++mi)
        #pragma unroll
        for (int ni = 0; ni < 4; ++ni)
          acc[mi][ni] = __builtin_amdgcn_mfma_f32_16x16x32_bf16(af[mi], bfr[ni], acc[mi][ni], 0, 0, 0);
    }
    __syncthreads();
  }

  if (z == 2) {
    #pragma unroll
    for (int mi = 0; mi < 4; ++mi) {
      #pragma unroll
      for (int ni = 0; ni < 4; ++ni) {
        int col = bn0 + wn * 64 + ni * 16 + q;
        float bb = bias[col];
        int h = col >> 6, d = col & 63;
        int row0 = bm0 + wm * 64 + mi * 16 + 4 * g;
        int b = row0 >> 11, n0 = row0 & 2047;
        ushort4 o4;
        o4.x = f2bf(acc[mi][ni][0] + bb);
        o4.y = f2bf(acc[mi][ni][1] + bb);
        o4.z = f2bf(acc[mi][ni][2] + bb);
        o4.w = f2bf(acc[mi][ni][3] + bb);
        *reinterpret_cast<ushort4*>(&Ovt[(((b << 4) + h) * 64 + d) * 2048 + n0]) = o4;
      }
    }
  } else {
    u16* O = (z == 0) ? Oq : Ok;
    #pragma unroll
    for (int mi = 0; mi < 4; ++mi) {
      #pragma unroll
      for (int ni = 0; ni < 4; ++ni) {
        int col = bn0 + wn * 64 + ni * 16 + q;
        float bb = bias[col];
        int h = col >> 6, d = col & 63;
        #pragma unroll
        for (int r = 0; r < 4; ++r) {
          int row = bm0 + wm * 64 + mi * 16 + 4 * g + r;
          int b = row >> 11, n = row & 2047;
          float v = (acc[mi][ni][r] + bb) * scale;
          O[(((b << 4) + h) * 2048 + n) * 64 + d] = f2bf(v);
        }
      }
    }
  }
}

// ---------------- flash attention: 4 waves, QBLK=64/wave, phase-drift design ----
// Waves 0-1: keys [0,1024); waves 2-3: keys [1024,2048). Each wave owns 64
// q-rows (qw = w&1). 2 blocks/CU, 2 waves/SIMD from DIFFERENT blocks -> no
// common barrier -> natural phase drift. 256-reg budget: all state in VGPRs.
// Swapped QK^T; O^T = V^T @ P^T; static-max softmax; T12 cvt_pk+permlane.
// Per tile: issue DMA(t+1) -> compute cur -> __syncthreads (sound staging).
__global__ __launch_bounds__(256, 2) void attn_kernel(
    const u16* __restrict__ Q, const u16* __restrict__ K, const u16* __restrict__ Vt,
    float* __restrict__ out)
{
  __shared__ __align__(16) u16 smem[32768];   // 64KB: per half {K[2][4096] | V[2][4096]}

  const int tid = threadIdx.x;
  const int lane = tid & 63, w = tid >> 6;          // 4 waves
  const int half = w >> 1, qw = w & 1;
  const int th128 = (qw << 6) + lane;               // thread idx within half (0..127)
  const int ql = lane & 31, h = lane >> 5, l7 = lane & 7;

  // XCD swizzle: xcd = lin&7 owns bh in [xcd*4, xcd*4+4)
  const int lin = blockIdx.x;
  const int xcd = lin & 7, li = lin >> 3;
  const int bh = xcd * 4 + (li >> 4);
  const int b = bh >> 4, hd = bh & 15;
  const int qrow0 = (li & 15) * 128 + qw * 64;      // this wave's 64 q-rows

  const u16* Qp = Q + (bh * 2048 + qrow0) * 64;
  const u16* Kp = K + (bh * 2048 + half * 1024) * 64;
  const u16* Vp = Vt + bh * 64 * 2048 + half * 1024;  // [64 d][2048 n]

  // Q fragments: qf[qh][ks], lane ql holds Q[qrow0 + qh*32 + ql][16ks + 8h + j]
  bf16x8 qf[2][4];
  #pragma unroll
  for (int qh = 0; qh < 2; ++qh)
    #pragma unroll
    for (int ks = 0; ks < 4; ++ks)
      qf[qh][ks] = *reinterpret_cast<const bf16x8*>(Qp + (qh * 32 + ql) * 64 + 16 * ks + 8 * h);

  // staging geometry: 512 16B-chunks per 8KB tile, 4 per thread (128 threads/half)
  int srow[4], scb[4];
  #pragma unroll
  for (int i = 0; i < 4; ++i) {
    int c = i * 128 + th128;
    srow[i] = c >> 3;
    scb[i] = 16 * ((c & 7) ^ ((c >> 3) & 7));
  }

  u16* Kh = smem + half * 16384;
  u16* Vh = Kh + 8192;

  f32x16 o00, o01, o10, o11;   // o[dt][qh]
  #pragma unroll
  for (int i = 0; i < 16; ++i) { o00[i] = 0.f; o01[i] = 0.f; o10[i] = 0.f; o11[i] = 0.f; }
  float ls0 = 0.0f, ls1 = 0.0f;

  // prologue: stage tile 0
  {
    #pragma unroll
    for (int i = 0; i < 4; ++i) {
      int c8 = (i * 128 + th128) * 8;
      gload_lds16((const char*)(Kp + srow[i] * 64) + scb[i], &Kh[c8]);
      gload_lds16((const char*)(Vp + srow[i] * 2048) + scb[i], &Vh[c8]);
    }
    __syncthreads();
  }

  for (int t = 0; t < 16; ++t) {
    const int cur = t & 1, nxt = cur ^ 1;
    if (t < 15) {  // issue next-tile DMA (lands under this tile's compute)
      const int kbn = t * 64 + 64;
      #pragma unroll
      for (int i = 0; i < 4; ++i) {
        int c8 = (i * 128 + th128) * 8;
        gload_lds16((const char*)(Kp + (kbn + srow[i]) * 64) + scb[i], &Kh[nxt * 4096 + c8]);
        gload_lds16((const char*)(Vp + srow[i] * 2048 + kbn) + scb[i], &Vh[nxt * 4096 + c8]);
      }
    }

    // ---- QK^T: p[kt][qh], 16 MFMA, 8 kf reads (each feeds both q-halves) ----
    f32x16 p00, p01, p10, p11;
    #pragma unroll
    for (int i = 0; i < 16; ++i) { p00[i] = 0.f; p01[i] = 0.f; p10[i] = 0.f; p11[i] = 0.f; }
    const u16* kl = Kh + cur * 4096;
    __builtin_amdgcn_s_setprio(1);
    #pragma unroll
    for (int ks = 0; ks < 4; ++ks) {
      int cb = (16 * ks + 8 * h) ^ (l7 << 3);
      bf16x8 kf0 = *reinterpret_cast<const bf16x8*>(kl + ql * 64 + cb);
      p00 = __builtin_amdgcn_mfma_f32_32x32x16_bf16(kf0, qf[0][ks], p00, 0, 0, 0);
      p01 = __builtin_amdgcn_mfma_f32_32x32x16_bf16(kf0, qf[1][ks], p01, 0, 0, 0);
      bf16x8 kf1 = *reinterpret_cast<const bf16x8*>(kl + (32 + ql) * 64 + cb);
      p10 = __builtin_amdgcn_mfma_f32_32x32x16_bf16(kf1, qf[0][ks], p10, 0, 0, 0);
      p11 = __builtin_amdgcn_mfma_f32_32x32x16_bf16(kf1, qf[1][ks], p11, 0, 0, 0);
    }
    __builtin_amdgcn_s_setprio(0);

    // ---- hoisted V-frag reads for dt=0 (latency hides under softmax) ----
    const u16* vl = Vh + cur * 4096;
    bf16x8 vfa[4];
    #pragma unroll
    for (int sl = 0; sl < 4; ++sl) {
      int cb = (16 * sl + 8 * h) ^ (l7 << 3);
      vfa[sl] = *reinterpret_cast<const bf16x8*>(vl + ql * 64 + cb);
    }

    // ---- static-max softmax (log2 domain; Q pre-scaled by log2e/32) ----
    #pragma unroll
    for (int i = 0; i < 16; ++i) {
      p00[i] = __builtin_amdgcn_exp2f(p00[i]);
      p01[i] = __builtin_amdgcn_exp2f(p01[i]);
      p10[i] = __builtin_amdgcn_exp2f(p10[i]);
      p11[i] = __builtin_amdgcn_exp2f(p11[i]);
    }
    {
      float s0 = 0.f, s1 = 0.f;
      #pragma unroll
      for (int i = 0; i < 16; ++i) { s0 += p00[i] + p10[i]; s1 += p01[i] + p11[i]; }
      s0 += __shfl_xor(s0, 32);
      s1 += __shfl_xor(s1, 32);
      ls0 += s0; ls1 += s1;
    }

    // ---- P^T -> bf16 B-fragments: pf[slice][qh] ----
    bf16x8 pf[4][2];
    p_to_pf(p00, pf[0][0], pf[1][0]);
    p_to_pf(p10, pf[2][0], pf[3][0]);
    p_to_pf(p01, pf[0][1], pf[1][1]);
    p_to_pf(p11, pf[2][1], pf[3][1]);

    // ---- PV: o[dt][qh] += V^T-slice @ P^T-slice, 16 MFMA, 8 vf reads ----
    __builtin_amdgcn_s_setprio(1);
    #pragma unroll
    for (int sl = 0; sl < 4; ++sl) {
      o00 = __builtin_amdgcn_mfma_f32_32x32x16_bf16(vfa[sl], pf[sl][0], o00, 0, 0, 0);
      o01 = __builtin_amdgcn_mfma_f32_32x32x16_bf16(vfa[sl], pf[sl][1], o01, 0, 0, 0);
      int cb = (16 * sl + 8 * h) ^ (l7 << 3);
      bf16x8 vf1 = *reinterpret_cast<const bf16x8*>(vl + (32 + ql) * 64 + cb);
      o10 = __builtin_amdgcn_mfma_f32_32x32x16_bf16(vf1, pf[sl][0], o10, 0, 0, 0);
      o11 = __builtin_amdgcn_mfma_f32_32x32x16_bf16(vf1, pf[sl][1], o11, 0, 0, 0);
    }
    __builtin_amdgcn_s_setprio(0);

    __syncthreads();   // drains DMA(t+1) (full tile to land) + buffer safety
  }

  // ---- combine key-halves in LDS (static-max => linear) ----
  float* Of = reinterpret_cast<float*>(smem);
  float* Lf = Of + 128 * 66;
  const int obase = (qw * 64 + lane) * 66;
  if (half == 1) {
    #pragma unroll
    for (int i = 0; i < 16; ++i) {
      Of[obase + i]      = o00[i];
      Of[obase + 16 + i] = o01[i];
      Of[obase + 32 + i] = o10[i];
      Of[obase + 48 + i] = o11[i];
    }
    Lf[qw * 64 + lane] = ls0;
    Lf[128 + qw * 64 + lane] = ls1;
  }
  __syncthreads();
  if (half == 0) {
    #pragma unroll
    for (int i = 0; i < 16; ++i) {
      o00[i] += Of[obase + i];
      o01[i] += Of[obase + 16 + i];
      o10[i] += Of[obase + 32 + i];
      o11[i] += Of[obase + 48 + i];
    }
    ls0 += Lf[qw * 64 + lane];
    ls1 += Lf[128 + qw * 64 + lane];

    float r0 = 1.0f / ls0, r1 = 1.0f / ls1;
    float* op0 = out + ((size_t)(b * 2048 + qrow0 + ql) * 1024 + hd * 64);
    float* op1 = out + ((size_t)(b * 2048 + qrow0 + 32 + ql) * 1024 + hd * 64);
    #pragma unroll
    for (int g2 = 0; g2 < 4; ++g2) {
      float4 v;
      v.x = o00[4 * g2 + 0] * r0; v.y = o00[4 * g2 + 1] * r0;
      v.z = o00[4 * g2 + 2] * r0; v.w = o00[4 * g2 + 3] * r0;
      *reinterpret_cast<float4*>(op0 + 8 * g2 + 4 * h) = v;
      v.x = o10[4 * g2 + 0] * r0; v.y = o10[4 * g2 + 1] * r0;
      v.z = o10[4 * g2 + 2] * r0; v.w = o10[4 * g2 + 3] * r0;
      *reinterpret_cast<float4*>(op0 + 32 + 8 * g2 + 4 * h) = v;
      v.x = o01[4 * g2 + 0] * r1; v.y = o01[4 * g2 + 1] * r1;
      v.z = o01[4 * g2 + 2] * r1; v.w = o01[4 * g2 + 3] * r1;
      *reinterpret_cast<float4*>(op1 + 8 * g2 + 4 * h) = v;
      v.x = o11[4 * g2 + 0] * r1; v.y = o11[4 * g2 + 1] * r1;
      v.z = o11[4 * g2 + 2] * r1; v.w = o11[4 * g2 + 3] * r1;
      *reinterpret_cast<float4*>(op1 + 32 + 8 * g2 + 4 * h) = v;
    }
  }
}

extern "C" void kernel_launch(void* const* d_in, const int* in_sizes, int n_in,
                              void* d_out, int out_size, void* d_ws, size_t ws_size,
                              hipStream_t stream) {
  const float* x  = (const float*)d_in[0];
  const float* Wq = (const float*)d_in[1];
  const float* bq = (const float*)d_in[2];
  const float* Wk = (const float*)d_in[3];
  const float* bk = (const float*)d_in[4];
  const float* Wv = (const float*)d_in[5];
  const float* bv = (const float*)d_in[6];
  float* out = (float*)d_out;

  u16* ws  = (u16*)d_ws;
  u16* xb  = ws;                  // 4096*1024
  u16* wqb = xb  + 4194304;       // 1024*1024
  u16* wkb = wqb + 1048576;
  u16* wvb = wkb + 1048576;
  u16* qb  = wvb + 1048576;       // [32][2048][64]
  u16* kb  = qb  + 4194304;
  u16* vt  = kb  + 4194304;       // [32][64][2048] (written transposed by gemm z==2)

  cvt_all<<<7168, 256, 0, stream>>>(x, Wq, Wk, Wv, ws);

  gemm_qkv<<<dim3(32, 8, 3), 256, 0, stream>>>(xb, wqb, wkb, wvb, bq, bk, bv, qb, kb, vt);

  attn_kernel<<<512, 256, 0, stream>>>(qb, kb, vt, out);
}